// Round 1
// baseline (747.352 us; speedup 1.0000x reference)
//
#include <hip/hip_runtime.h>
#include <math.h>

#define Bsz 64
#define T 32
#define H 768
#define E 8
#define NB 2
#define DFF 3072
#define NBEAM (Bsz * NB)   // 128

// d_out layout (floats, concatenated in return order):
// [0)                         output      128*32*768 = 3145728
// [3145728)                   beam_scores 128
// [3145856)                   expert_route 128 (int values stored as float)
// [3145984)                   beam_idx     128 (int values stored as float)
// [3146112)                   importance_loss 1
#define OUT_BS 3145728
#define OUT_ER 3145856
#define OUT_BI 3145984
#define OUT_IL 3146112

// ws layout (float units):
// [0, 512)    logits (64 x 8)
// [512, 640)  beam weight (128)
// [640, 768)  beam expert id (int, 128)
// [1024, ...) h buffer: 128 * 32 * 3072 floats = 50.3 MB
#define WS_LOGITS 0
#define WS_BEAMW  512
#define WS_BEAME  640
#define WS_HBUF   1024

// ---------------------------------------------------------------------------
// Kernel 1: per-batch-row x_avg + gate logits.  grid=64 blocks, 256 threads.
// ---------------------------------------------------------------------------
__global__ __launch_bounds__(256) void gate_logits_kernel(
    const float* __restrict__ x, const float* __restrict__ gate_w,
    float* __restrict__ logits)
{
    __shared__ float avg[H];
    const int b = blockIdx.x, tid = threadIdx.x;
    for (int c = tid; c < H; c += 256) {
        const float* xp = x + (size_t)b * T * H + c;
        float s = 0.f;
        #pragma unroll
        for (int t = 0; t < T; ++t) s += xp[t * H];
        avg[c] = s * (1.0f / T);
    }
    __syncthreads();
    // 8 experts x 32 lanes each
    const int e = tid >> 5, l = tid & 31;
    float p = 0.f;
    for (int c = l; c < H; c += 32) p += avg[c] * gate_w[e * H + c];
    #pragma unroll
    for (int off = 16; off; off >>= 1) p += __shfl_down(p, off, 32);
    if (l == 0) logits[b * E + e] = p;
}

// ---------------------------------------------------------------------------
// Kernel 2: softmax, top-2, beam outputs, importance loss. 1 block, 64 thr.
// ---------------------------------------------------------------------------
__global__ __launch_bounds__(64) void gating_kernel(
    const float* __restrict__ logits, float* __restrict__ beam_w,
    int* __restrict__ beam_e, float* __restrict__ dout)
{
    __shared__ float sc[Bsz][E];
    const int r = threadIdx.x;  // 0..63
    float v[E];
    float mx = -1e30f;
    #pragma unroll
    for (int e = 0; e < E; ++e) { v[e] = logits[r * E + e]; mx = fmaxf(mx, v[e]); }
    float s = 0.f;
    #pragma unroll
    for (int e = 0; e < E; ++e) { v[e] = expf(v[e] - mx); s += v[e]; }
    const float inv = 1.0f / s;
    #pragma unroll
    for (int e = 0; e < E; ++e) { v[e] *= inv; sc[r][e] = v[e]; }
    // top-2, stable (lower index wins ties) — matches jax.lax.top_k
    float v0 = -1.f, v1 = -1.f; int i0 = 0, i1 = 0;
    #pragma unroll
    for (int e = 0; e < E; ++e) {
        if (v[e] > v0)      { v1 = v0; i1 = i0; v0 = v[e]; i0 = e; }
        else if (v[e] > v1) { v1 = v[e]; i1 = e; }
    }
    const int b0 = 2 * r, b1 = 2 * r + 1;
    dout[OUT_BS + b0] = v0;          dout[OUT_BS + b1] = v1;
    dout[OUT_ER + b0] = (float)i0;   dout[OUT_ER + b1] = (float)i1;
    dout[OUT_BI + b0] = (float)b0;   dout[OUT_BI + b1] = (float)b1;
    beam_w[b0] = v0;  beam_w[b1] = v1;
    beam_e[b0] = i0;  beam_e[b1] = i1;
    __syncthreads();
    if (r == 0) {
        float imp[E];
        float tot = 0.f;
        #pragma unroll
        for (int e = 0; e < E; ++e) {
            float a = 0.f;
            for (int rr = 0; rr < Bsz; ++rr) a += sc[rr][e];
            imp[e] = a; tot += a;
        }
        const float mean = tot / E;
        float var = 0.f;
        #pragma unroll
        for (int e = 0; e < E; ++e) { float d = imp[e] - mean; var += d * d; }
        var /= (E - 1);  // ddof=1
        dout[OUT_IL] = var / (mean * mean);
    }
}

// ---------------------------------------------------------------------------
// FFN GEMM: C[t][n] = act(sum_k A[t][k] * W[n][k] + bias[n]) [* scale]
// Both A and W are K-contiguous (NT GEMM). Block tile: 32(t) x 128(n), Kt=32.
// Thread tile 4x4, threads = 8(t-groups) x 32(n-groups) = 256.
// LDS holds K-major transposed tiles so compute reads are ds_read_b128.
// KTOT: 768 (gemm1) / 3072 (gemm2). DO_GELU selects gelu vs scale-by-weight.
// ---------------------------------------------------------------------------
template <int KTOT, bool DO_GELU>
__global__ __launch_bounds__(256, 2) void moe_ffn_gemm(
    const float* __restrict__ Abase, int a_div,       // A row = KTOT floats
    const float* __restrict__ Wbase, int w_rows,      // expert stride = w_rows*KTOT
    const float* __restrict__ biasbase,
    const int* __restrict__ beam_e, const float* __restrict__ beam_w,
    float* __restrict__ Obase)                        // beam stride = T*w_rows
{
    __shared__ float sA[32][36];    // [k][t], pad 4 keeps float4 alignment
    __shared__ float sB[32][132];   // [k][n]

    const int b  = blockIdx.y;
    const int f0 = blockIdx.x * 128;
    const int e  = beam_e[b];
    const float* A = Abase + (size_t)(b / a_div) * T * KTOT;
    const float* W = Wbase + (size_t)e * w_rows * KTOT + (size_t)f0 * KTOT;

    const int tid = threadIdx.x;
    const int tt = tid >> 5;     // 0..7  -> t = tt*4 + i
    const int tf = tid & 31;     // 0..31 -> n = tf*4 + j

    // staging indices
    const int at = tid >> 3;         // 0..31  (t row for A, base-f for W)
    const int ak = (tid & 7) * 4;    // 0,4,...,28

    float acc[4][4];
    #pragma unroll
    for (int i = 0; i < 4; ++i)
        #pragma unroll
        for (int j = 0; j < 4; ++j) acc[i][j] = 0.f;

    for (int k0 = 0; k0 < KTOT; k0 += 32) {
        const float4 av = *(const float4*)(A + (size_t)at * KTOT + k0 + ak);
        float4 bv[4];
        #pragma unroll
        for (int r = 0; r < 4; ++r) {
            const int f = r * 32 + at;
            bv[r] = *(const float4*)(W + (size_t)f * KTOT + k0 + ak);
        }
        __syncthreads();   // previous iteration's compute done before overwrite
        sA[ak + 0][at] = av.x; sA[ak + 1][at] = av.y;
        sA[ak + 2][at] = av.z; sA[ak + 3][at] = av.w;
        #pragma unroll
        for (int r = 0; r < 4; ++r) {
            const int f = r * 32 + at;
            sB[ak + 0][f] = bv[r].x; sB[ak + 1][f] = bv[r].y;
            sB[ak + 2][f] = bv[r].z; sB[ak + 3][f] = bv[r].w;
        }
        __syncthreads();
        #pragma unroll
        for (int k = 0; k < 32; ++k) {
            const float4 a4 = *(const float4*)(&sA[k][tt * 4]);
            const float4 b4 = *(const float4*)(&sB[k][tf * 4]);
            const float a_[4] = {a4.x, a4.y, a4.z, a4.w};
            const float b_[4] = {b4.x, b4.y, b4.z, b4.w};
            #pragma unroll
            for (int i = 0; i < 4; ++i)
                #pragma unroll
                for (int j = 0; j < 4; ++j) acc[i][j] += a_[i] * b_[j];
        }
    }

    const float4 bias4 = *(const float4*)(biasbase + (size_t)e * w_rows + f0 + tf * 4);
    const float bias_[4] = {bias4.x, bias4.y, bias4.z, bias4.w};
    const float scale = DO_GELU ? 1.0f : beam_w[b];
    float* O = Obase + (size_t)b * T * w_rows + f0;
    #pragma unroll
    for (int i = 0; i < 4; ++i) {
        const int t = tt * 4 + i;
        float4 o;
        float tmp[4];
        #pragma unroll
        for (int j = 0; j < 4; ++j) {
            float vv = acc[i][j] + bias_[j];
            if (DO_GELU) {
                vv = 0.5f * vv * (1.0f + erff(vv * 0.70710678118654752f));
            } else {
                vv *= scale;
            }
            tmp[j] = vv;
        }
        o.x = tmp[0]; o.y = tmp[1]; o.z = tmp[2]; o.w = tmp[3];
        *(float4*)(O + (size_t)t * w_rows + tf * 4) = o;
    }
}

extern "C" void kernel_launch(void* const* d_in, const int* in_sizes, int n_in,
                              void* d_out, int out_size, void* d_ws, size_t ws_size,
                              hipStream_t stream)
{
    const float* x      = (const float*)d_in[0];
    const float* gate_w = (const float*)d_in[1];
    const float* w1     = (const float*)d_in[2];
    const float* b1     = (const float*)d_in[3];
    const float* w2     = (const float*)d_in[4];
    const float* b2     = (const float*)d_in[5];
    float* out = (float*)d_out;
    float* ws  = (float*)d_ws;

    float* logits = ws + WS_LOGITS;
    float* beam_w = ws + WS_BEAMW;
    int*   beam_e = (int*)(ws + WS_BEAME);
    float* hbuf   = ws + WS_HBUF;   // 128*32*3072 floats

    gate_logits_kernel<<<Bsz, 256, 0, stream>>>(x, gate_w, logits);
    gating_kernel<<<1, 64, 0, stream>>>(logits, beam_w, beam_e, out);
    // GEMM1 + GELU: per beam, selected expert: (32x768) @ (3072x768)^T
    moe_ffn_gemm<H, true><<<dim3(DFF / 128, NBEAM), 256, 0, stream>>>(
        x, NB, w1, DFF, b1, beam_e, nullptr, hbuf);
    // GEMM2 + scale: (32x3072) @ (768x3072)^T
    moe_ffn_gemm<DFF, false><<<dim3(H / 128, NBEAM), 256, 0, stream>>>(
        hbuf, 1, w2, H, b2, beam_e, beam_w, out);
}

// Round 2
// 543.467 us; speedup vs baseline: 1.3752x; 1.3752x over previous
//
#include <hip/hip_runtime.h>
#include <hip/hip_bf16.h>
#include <math.h>

#define Bsz 64
#define T 32
#define H 768
#define E 8
#define NB 2
#define DFF 3072
#define NBEAM (Bsz * NB)   // 128

// d_out layout (floats):
#define OUT_BS 3145728
#define OUT_ER 3145856
#define OUT_BI 3145984
#define OUT_IL 3146112

// ws layout (float units):
// [0,512) logits | [512,640) beam_w | [640,768) beam_e | [1024,...) x_bf | then h_bf
#define WS_LOGITS 0
#define WS_BEAMW  512
#define WS_BEAME  640
#define WS_XBF    1024                       // x bf16: 1,572,864 el = 786,432 floats
#define WS_HBF    (1024 + 786432)            // h bf16: 12,582,912 el = 6,291,456 floats
// total ~28.3 MB (< the 50.3 MB proven in R1)

typedef __attribute__((ext_vector_type(8))) short short8;
typedef __attribute__((ext_vector_type(4))) float f32x4;

// ---------------------------------------------------------------------------
// fp32 -> bf16x8 (RNE) from contiguous memory, for MFMA B fragments
// ---------------------------------------------------------------------------
__device__ __forceinline__ short8 load_cvt8(const float* __restrict__ p) {
    const float4 u = *(const float4*)p;
    const float4 v = *(const float4*)(p + 4);
    union { short8 s; unsigned w[4]; } r;
    __hip_bfloat162 t;
    t = __float22bfloat162_rn(make_float2(u.x, u.y)); r.w[0] = *(unsigned*)&t;
    t = __float22bfloat162_rn(make_float2(u.z, u.w)); r.w[1] = *(unsigned*)&t;
    t = __float22bfloat162_rn(make_float2(v.x, v.y)); r.w[2] = *(unsigned*)&t;
    t = __float22bfloat162_rn(make_float2(v.z, v.w)); r.w[3] = *(unsigned*)&t;
    return r.s;
}

// ---------------------------------------------------------------------------
// Convert x fp32 -> bf16 (4 elements / thread)
// ---------------------------------------------------------------------------
__global__ __launch_bounds__(256) void conv_x_kernel(
    const float* __restrict__ x, ushort* __restrict__ xb, int n4)
{
    const int i = blockIdx.x * 256 + threadIdx.x;
    if (i >= n4) return;
    const float4 v = ((const float4*)x)[i];
    __hip_bfloat162 t0 = __float22bfloat162_rn(make_float2(v.x, v.y));
    __hip_bfloat162 t1 = __float22bfloat162_rn(make_float2(v.z, v.w));
    ushort4 o;
    o.x = (*(unsigned*)&t0) & 0xffff; o.y = (*(unsigned*)&t0) >> 16;
    o.z = (*(unsigned*)&t1) & 0xffff; o.w = (*(unsigned*)&t1) >> 16;
    ((ushort4*)xb)[i] = o;
}

// ---------------------------------------------------------------------------
// Gate logits: per-batch x_avg + logits. grid=64, 256 thr. (fp32, exact)
// ---------------------------------------------------------------------------
__global__ __launch_bounds__(256) void gate_logits_kernel(
    const float* __restrict__ x, const float* __restrict__ gate_w,
    float* __restrict__ logits)
{
    __shared__ float avg[H];
    const int b = blockIdx.x, tid = threadIdx.x;
    for (int c = tid; c < H; c += 256) {
        const float* xp = x + (size_t)b * T * H + c;
        float s = 0.f;
        #pragma unroll
        for (int t = 0; t < T; ++t) s += xp[t * H];
        avg[c] = s * (1.0f / T);
    }
    __syncthreads();
    const int e = tid >> 5, l = tid & 31;
    float p = 0.f;
    for (int c = l; c < H; c += 32) p += avg[c] * gate_w[e * H + c];
    #pragma unroll
    for (int off = 16; off; off >>= 1) p += __shfl_down(p, off, 32);
    if (l == 0) logits[b * E + e] = p;
}

// ---------------------------------------------------------------------------
// Softmax, top-2, beam outputs, importance loss. 1 block, 64 thr. (fp32)
// ---------------------------------------------------------------------------
__global__ __launch_bounds__(64) void gating_kernel(
    const float* __restrict__ logits, float* __restrict__ beam_w,
    int* __restrict__ beam_e, float* __restrict__ dout)
{
    __shared__ float sc[Bsz][E];
    const int r = threadIdx.x;
    float v[E];
    float mx = -1e30f;
    #pragma unroll
    for (int e = 0; e < E; ++e) { v[e] = logits[r * E + e]; mx = fmaxf(mx, v[e]); }
    float s = 0.f;
    #pragma unroll
    for (int e = 0; e < E; ++e) { v[e] = expf(v[e] - mx); s += v[e]; }
    const float inv = 1.0f / s;
    #pragma unroll
    for (int e = 0; e < E; ++e) { v[e] *= inv; sc[r][e] = v[e]; }
    float v0 = -1.f, v1 = -1.f; int i0 = 0, i1 = 0;
    #pragma unroll
    for (int e = 0; e < E; ++e) {
        if (v[e] > v0)      { v1 = v0; i1 = i0; v0 = v[e]; i0 = e; }
        else if (v[e] > v1) { v1 = v[e]; i1 = e; }
    }
    const int b0 = 2 * r, b1 = 2 * r + 1;
    dout[OUT_BS + b0] = v0;          dout[OUT_BS + b1] = v1;
    dout[OUT_ER + b0] = (float)i0;   dout[OUT_ER + b1] = (float)i1;
    dout[OUT_BI + b0] = (float)b0;   dout[OUT_BI + b1] = (float)b1;
    beam_w[b0] = v0;  beam_w[b1] = v1;
    beam_e[b0] = i0;  beam_e[b1] = i1;
    __syncthreads();
    if (r == 0) {
        float imp[E]; float tot = 0.f;
        #pragma unroll
        for (int e = 0; e < E; ++e) {
            float a = 0.f;
            for (int rr = 0; rr < Bsz; ++rr) a += sc[rr][e];
            imp[e] = a; tot += a;
        }
        const float mean = tot / E;
        float var = 0.f;
        #pragma unroll
        for (int e = 0; e < E; ++e) { float d = imp[e] - mean; var += d * d; }
        var /= (E - 1);
        dout[OUT_IL] = var / (mean * mean);
    }
}

// ---------------------------------------------------------------------------
// MFMA GEMM, no LDS. C[m][n] = act(sum_k A[m][k]*W[n][k] + bias[n]) [*scale]
// A: bf16 [rows][KTOT] K-contiguous. W: fp32 [E][w_rows][KTOT], cvt on the fly.
// Block: 256 thr = 4 waves, tile 32(m) x 128(n); wave tile 32x32 via 2x2 of
// 16x16x32 MFMAs. Fragment layouts (m89/m120-verified):
//   A/B operand: row = lane&15, k = (lane>>4)*8 + j   (16B contiguous load)
//   C/D:         col = lane&15, row = (lane>>4)*4 + reg
// ---------------------------------------------------------------------------
template <int KTOT, bool DO_GELU>
__global__ __launch_bounds__(256) void moe_ffn_mfma(
    const ushort* __restrict__ Abf, int a_div,
    const float* __restrict__ Wf32, int w_rows,
    const float* __restrict__ biasb,
    const int* __restrict__ beam_e, const float* __restrict__ beam_w,
    void* __restrict__ Obase)
{
    const int b    = blockIdx.y;
    const int e    = beam_e[b];
    const int wv   = threadIdx.x >> 6;
    const int lane = threadIdx.x & 63;
    const int quad = lane >> 4;
    const int l16  = lane & 15;
    const int n0   = blockIdx.x * 128 + wv * 32;

    const ushort* A = Abf + (size_t)(b / a_div) * T * KTOT
                    + (size_t)l16 * KTOT + quad * 8;
    const float* W = Wf32 + (size_t)e * w_rows * KTOT
                   + (size_t)(n0 + l16) * KTOT + quad * 8;

    f32x4 acc[2][2] = {{{0.f,0.f,0.f,0.f},{0.f,0.f,0.f,0.f}},
                       {{0.f,0.f,0.f,0.f},{0.f,0.f,0.f,0.f}}};

    #pragma unroll 2
    for (int k0 = 0; k0 < KTOT; k0 += 32) {
        const short8 a0 = *(const short8*)(A + k0);
        const short8 a1 = *(const short8*)(A + 16 * KTOT + k0);
        const short8 b0 = load_cvt8(W + k0);
        const short8 b1 = load_cvt8(W + (size_t)16 * KTOT + k0);
        acc[0][0] = __builtin_amdgcn_mfma_f32_16x16x32_bf16(a0, b0, acc[0][0], 0, 0, 0);
        acc[0][1] = __builtin_amdgcn_mfma_f32_16x16x32_bf16(a0, b1, acc[0][1], 0, 0, 0);
        acc[1][0] = __builtin_amdgcn_mfma_f32_16x16x32_bf16(a1, b0, acc[1][0], 0, 0, 0);
        acc[1][1] = __builtin_amdgcn_mfma_f32_16x16x32_bf16(a1, b1, acc[1][1], 0, 0, 0);
    }

    const float scale = DO_GELU ? 1.0f : beam_w[b];
    #pragma unroll
    for (int nt = 0; nt < 2; ++nt) {
        const int n = n0 + nt * 16 + l16;
        const float bias = biasb[(size_t)e * w_rows + n];
        #pragma unroll
        for (int mt = 0; mt < 2; ++mt) {
            #pragma unroll
            for (int r = 0; r < 4; ++r) {
                const int m = mt * 16 + quad * 4 + r;
                float vv = acc[mt][nt][r] + bias;
                const size_t idx = (size_t)b * T * w_rows + (size_t)m * w_rows + n;
                if (DO_GELU) {
                    vv = 0.5f * vv * (1.0f + erff(vv * 0.70710678118654752f));
                    ((__hip_bfloat16*)Obase)[idx] = __float2bfloat16(vv);
                } else {
                    ((float*)Obase)[idx] = vv * scale;
                }
            }
        }
    }
}

extern "C" void kernel_launch(void* const* d_in, const int* in_sizes, int n_in,
                              void* d_out, int out_size, void* d_ws, size_t ws_size,
                              hipStream_t stream)
{
    const float* x      = (const float*)d_in[0];
    const float* gate_w = (const float*)d_in[1];
    const float* w1     = (const float*)d_in[2];
    const float* b1     = (const float*)d_in[3];
    const float* w2     = (const float*)d_in[4];
    const float* b2     = (const float*)d_in[5];
    float* out = (float*)d_out;
    float* ws  = (float*)d_ws;

    float*  logits = ws + WS_LOGITS;
    float*  beam_w = ws + WS_BEAMW;
    int*    beam_e = (int*)(ws + WS_BEAME);
    ushort* x_bf   = (ushort*)(ws + WS_XBF);
    ushort* h_bf   = (ushort*)(ws + WS_HBF);

    conv_x_kernel<<<(Bsz * T * H / 4 + 255) / 256, 256, 0, stream>>>(
        x, x_bf, Bsz * T * H / 4);
    gate_logits_kernel<<<Bsz, 256, 0, stream>>>(x, gate_w, logits);
    gating_kernel<<<1, 64, 0, stream>>>(logits, beam_w, beam_e, out);
    // GEMM1 + GELU: (32x768)bf16 @ (3072x768)^T fp32->bf16, out bf16 h
    moe_ffn_mfma<H, true><<<dim3(DFF / 128, NBEAM), 256, 0, stream>>>(
        x_bf, NB, w1, DFF, b1, beam_e, nullptr, (void*)h_bf);
    // GEMM2 + scale: (32x3072)bf16 @ (768x3072)^T fp32->bf16, out fp32
    moe_ffn_mfma<DFF, false><<<dim3(H / 128, NBEAM), 256, 0, stream>>>(
        h_bf, 1, w2, H, b2, beam_e, beam_w, out);
}

// Round 3
// 537.269 us; speedup vs baseline: 1.3910x; 1.0115x over previous
//
#include <hip/hip_runtime.h>
#include <hip/hip_bf16.h>
#include <math.h>

#define Bsz 64
#define T 32
#define H 768
#define E 8
#define NB 2
#define DFF 3072
#define NBEAM (Bsz * NB)   // 128
#define NT4MAX 40          // max 4-beam tiles: sum ceil(cnt_e/4) <= (128+3*8)/4 = 38

// d_out layout (floats):
#define OUT_BS 3145728
#define OUT_ER 3145856
#define OUT_BI 3145984
#define OUT_IL 3146112

// ws layout (float units):
#define WS_LOGITS 0          // 512
#define WS_BEAMW  512        // 128
#define WS_SORT   768        // 128 int: beams sorted by expert
#define WS_T4E    896        // 40 int
#define WS_T4B    936        // 40 int
#define WS_T4C    976        // 40 int
#define WS_XBF    1024       // x bf16: 786432 floats
#define WS_HBF    (1024 + 786432)   // h bf16: 6291456 floats

typedef __attribute__((ext_vector_type(8))) short short8;
typedef __attribute__((ext_vector_type(4))) float f32x4;

__device__ __forceinline__ short8 load_cvt8(const float* __restrict__ p) {
    const float4 u = *(const float4*)p;
    const float4 v = *(const float4*)(p + 4);
    union { short8 s; unsigned w[4]; } r;
    __hip_bfloat162 t;
    t = __float22bfloat162_rn(make_float2(u.x, u.y)); r.w[0] = *(unsigned*)&t;
    t = __float22bfloat162_rn(make_float2(u.z, u.w)); r.w[1] = *(unsigned*)&t;
    t = __float22bfloat162_rn(make_float2(v.x, v.y)); r.w[2] = *(unsigned*)&t;
    t = __float22bfloat162_rn(make_float2(v.z, v.w)); r.w[3] = *(unsigned*)&t;
    return r.s;
}

// ---------------------------------------------------------------------------
// Gate logits + fused x->bf16 conversion. grid=64 blocks (one per batch).
// ---------------------------------------------------------------------------
__global__ __launch_bounds__(256) void gate_logits_kernel(
    const float* __restrict__ x, const float* __restrict__ gate_w,
    float* __restrict__ logits, ushort* __restrict__ xb)
{
    __shared__ float avg[H];
    const int b = blockIdx.x, tid = threadIdx.x;
    for (int c = tid; c < H; c += 256) {
        const float* xp = x  + (size_t)b * T * H + c;
        ushort*      xo = xb + (size_t)b * T * H + c;
        float s = 0.f;
        #pragma unroll
        for (int t = 0; t < T; ++t) {
            const float v = xp[t * H];
            s += v;
            __hip_bfloat16 hb = __float2bfloat16(v);
            xo[t * H] = *(ushort*)&hb;
        }
        avg[c] = s * (1.0f / T);
    }
    __syncthreads();
    const int e = tid >> 5, l = tid & 31;
    float p = 0.f;
    for (int c = l; c < H; c += 32) p += avg[c] * gate_w[e * H + c];
    #pragma unroll
    for (int off = 16; off; off >>= 1) p += __shfl_down(p, off, 32);
    if (l == 0) logits[b * E + e] = p;
}

// ---------------------------------------------------------------------------
// Softmax, top-2, beam outputs, importance loss, expert tile tables.
// 1 block, 64 threads.
// ---------------------------------------------------------------------------
__global__ __launch_bounds__(64) void gating_kernel(
    const float* __restrict__ logits, float* __restrict__ beam_w,
    int* __restrict__ sortb, int* __restrict__ t4e, int* __restrict__ t4b,
    int* __restrict__ t4c, float* __restrict__ dout)
{
    __shared__ float sc[Bsz][E];
    __shared__ int sexp[NBEAM];
    const int r = threadIdx.x;
    float v[E];
    float mx = -1e30f;
    #pragma unroll
    for (int e = 0; e < E; ++e) { v[e] = logits[r * E + e]; mx = fmaxf(mx, v[e]); }
    float s = 0.f;
    #pragma unroll
    for (int e = 0; e < E; ++e) { v[e] = expf(v[e] - mx); s += v[e]; }
    const float inv = 1.0f / s;
    #pragma unroll
    for (int e = 0; e < E; ++e) { v[e] *= inv; sc[r][e] = v[e]; }
    float v0 = -1.f, v1 = -1.f; int i0 = 0, i1 = 0;
    #pragma unroll
    for (int e = 0; e < E; ++e) {
        if (v[e] > v0)      { v1 = v0; i1 = i0; v0 = v[e]; i0 = e; }
        else if (v[e] > v1) { v1 = v[e]; i1 = e; }
    }
    const int b0 = 2 * r, b1 = 2 * r + 1;
    dout[OUT_BS + b0] = v0;          dout[OUT_BS + b1] = v1;
    dout[OUT_ER + b0] = (float)i0;   dout[OUT_ER + b1] = (float)i1;
    dout[OUT_BI + b0] = (float)b0;   dout[OUT_BI + b1] = (float)b1;
    beam_w[b0] = v0;  beam_w[b1] = v1;
    sexp[b0] = i0;    sexp[b1] = i1;
    __syncthreads();
    if (r == 0) {
        // importance loss
        float imp[E]; float tot = 0.f;
        #pragma unroll
        for (int e = 0; e < E; ++e) {
            float a = 0.f;
            for (int rr = 0; rr < Bsz; ++rr) a += sc[rr][e];
            imp[e] = a; tot += a;
        }
        const float mean = tot / E;
        float var = 0.f;
        #pragma unroll
        for (int e = 0; e < E; ++e) { float d = imp[e] - mean; var += d * d; }
        var /= (E - 1);
        dout[OUT_IL] = var / (mean * mean);
        // expert-grouped beam list + 4-beam tile table
        int cntE[E]; int offE[E]; int posE[E];
        #pragma unroll
        for (int e = 0; e < E; ++e) cntE[e] = 0;
        for (int b = 0; b < NBEAM; ++b) cntE[sexp[b]]++;
        int a0 = 0;
        #pragma unroll
        for (int e = 0; e < E; ++e) { offE[e] = a0; posE[e] = a0; a0 += cntE[e]; }
        for (int b = 0; b < NBEAM; ++b) sortb[posE[sexp[b]]++] = b;
        int t = 0;
        for (int e = 0; e < E; ++e) {
            for (int i = 0; i < cntE[e]; i += 4) {
                t4e[t] = e;
                t4b[t] = offE[e] + i;
                t4c[t] = (cntE[e] - i < 4) ? (cntE[e] - i) : 4;
                ++t;
            }
        }
        for (; t < NT4MAX; ++t) t4c[t] = 0;
    }
}

// ---------------------------------------------------------------------------
// Expert-grouped MFMA GEMM, no LDS.
// Block = (n-strip of NTILE, 4-beam tile): M = 128 rows of ONE expert.
// 4 waves; wave wv covers all 128 M-rows x NTILE/4 cols.
// A bf16 K-contiguous; W fp32 cvt on the fly.
// Fragment layouts (R2-verified): A/B row=lane&15, k=quad*8+j;
// C/D col=lane&15, row=quad*4+reg.
// ---------------------------------------------------------------------------
template <int KTOT, int NTILE, bool DO_GELU>
__global__ __launch_bounds__(256) void moe_ffn_mfma(
    const ushort* __restrict__ Abf, int a_div,
    const float* __restrict__ Wf32, int w_rows,
    const float* __restrict__ biasb,
    const int* __restrict__ sortb, const int* __restrict__ t4e,
    const int* __restrict__ t4b, const int* __restrict__ t4c,
    const float* __restrict__ beam_w,
    void* __restrict__ Obase)
{
    constexpr int NT = NTILE / 64;    // 16-col MFMA tiles per wave (2 or 1)
    const int tile = blockIdx.y;
    const int cnt  = t4c[tile];
    if (cnt == 0) return;
    const int e    = t4e[tile];
    const int base = t4b[tile];

    const int wv   = threadIdx.x >> 6;
    const int lane = threadIdx.x & 63;
    const int quad = lane >> 4;
    const int l16  = lane & 15;
    const int n0   = blockIdx.x * NTILE + wv * (NTILE / 4);

    int bm[4];
    #pragma unroll
    for (int s = 0; s < 4; ++s) bm[s] = sortb[base + (s < cnt ? s : cnt - 1)];

    const ushort* aptr[8];
    #pragma unroll
    for (int mt = 0; mt < 8; ++mt) {
        const int s = mt >> 1;
        aptr[mt] = Abf + (size_t)(bm[s] / a_div) * T * KTOT
                 + (size_t)((mt & 1) * 16 + l16) * KTOT + quad * 8;
    }
    const float* W = Wf32 + (size_t)e * w_rows * KTOT
                   + (size_t)(n0 + l16) * KTOT + quad * 8;

    f32x4 acc[8][NT];
    #pragma unroll
    for (int mt = 0; mt < 8; ++mt)
        #pragma unroll
        for (int nt = 0; nt < NT; ++nt) acc[mt][nt] = {0.f, 0.f, 0.f, 0.f};

    for (int k0 = 0; k0 < KTOT; k0 += 32) {
        short8 wf[NT];
        #pragma unroll
        for (int nt = 0; nt < NT; ++nt)
            wf[nt] = load_cvt8(W + (size_t)nt * 16 * KTOT + k0);
        short8 af[8];
        #pragma unroll
        for (int mt = 0; mt < 8; ++mt)
            af[mt] = *(const short8*)(aptr[mt] + k0);
        #pragma unroll
        for (int mt = 0; mt < 8; ++mt)
            #pragma unroll
            for (int nt = 0; nt < NT; ++nt)
                acc[mt][nt] = __builtin_amdgcn_mfma_f32_16x16x32_bf16(
                    af[mt], wf[nt], acc[mt][nt], 0, 0, 0);
    }

    #pragma unroll
    for (int nt = 0; nt < NT; ++nt) {
        const int n = n0 + nt * 16 + l16;
        const float bias = biasb[(size_t)e * w_rows + n];
        #pragma unroll
        for (int mt = 0; mt < 8; ++mt) {
            const int s = mt >> 1;
            if (s >= cnt) continue;
            const int b = bm[s];
            const float scale = DO_GELU ? 1.0f : beam_w[b];
            #pragma unroll
            for (int r = 0; r < 4; ++r) {
                const int row = (mt & 1) * 16 + quad * 4 + r;
                float vv = acc[mt][nt][r] + bias;
                const size_t idx = (size_t)b * T * w_rows + (size_t)row * w_rows + n;
                if (DO_GELU) {
                    vv = 0.5f * vv * (1.0f + erff(vv * 0.70710678118654752f));
                    ((__hip_bfloat16*)Obase)[idx] = __float2bfloat16(vv);
                } else {
                    ((float*)Obase)[idx] = vv * scale;
                }
            }
        }
    }
}

extern "C" void kernel_launch(void* const* d_in, const int* in_sizes, int n_in,
                              void* d_out, int out_size, void* d_ws, size_t ws_size,
                              hipStream_t stream)
{
    const float* x      = (const float*)d_in[0];
    const float* gate_w = (const float*)d_in[1];
    const float* w1     = (const float*)d_in[2];
    const float* b1     = (const float*)d_in[3];
    const float* w2     = (const float*)d_in[4];
    const float* b2     = (const float*)d_in[5];
    float* out = (float*)d_out;
    float* ws  = (float*)d_ws;

    float*  logits = ws + WS_LOGITS;
    float*  beam_w = ws + WS_BEAMW;
    int*    sortb  = (int*)(ws + WS_SORT);
    int*    t4e    = (int*)(ws + WS_T4E);
    int*    t4b    = (int*)(ws + WS_T4B);
    int*    t4c    = (int*)(ws + WS_T4C);
    ushort* x_bf   = (ushort*)(ws + WS_XBF);
    ushort* h_bf   = (ushort*)(ws + WS_HBF);

    gate_logits_kernel<<<Bsz, 256, 0, stream>>>(x, gate_w, logits, x_bf);
    gating_kernel<<<1, 64, 0, stream>>>(logits, beam_w, sortb, t4e, t4b, t4c, out);
    // GEMM1 + GELU: M=128 (4 beams), N-strips of 128 over DFF, K=768
    moe_ffn_mfma<H, 128, true><<<dim3(DFF / 128, NT4MAX), 256, 0, stream>>>(
        x_bf, NB, w1, DFF, b1, sortb, t4e, t4b, t4c, beam_w, (void*)h_bf);
    // GEMM2 + scale: M=128 (4 beams), N-strips of 64 over H, K=3072
    moe_ffn_mfma<DFF, 64, false><<<dim3(H / 64, NT4MAX), 256, 0, stream>>>(
        h_bf, 1, w2, H, b2, sortb, t4e, t4b, t4c, beam_w, out);
}

// Round 4
// 316.599 us; speedup vs baseline: 2.3606x; 1.6970x over previous
//
#include <hip/hip_runtime.h>
#include <hip/hip_bf16.h>
#include <math.h>

#define Bsz 64
#define T 32
#define H 768
#define E 8
#define NB 2
#define DFF 3072
#define NBEAM (Bsz * NB)   // 128
#define NT4MAX 40

// d_out layout (floats):
#define OUT_BS 3145728
#define OUT_ER 3145856
#define OUT_BI 3145984
#define OUT_IL 3146112

// ws layout (float units):
#define WS_LOGITS 0          // 512
#define WS_BEAMW  512        // 128
#define WS_SORT   768        // 128 int
#define WS_T4E    896        // 40 int
#define WS_T4B    936        // 40 int
#define WS_T4C    976        // 40 int
#define WS_XBF    1024       // x bf16: 786432 floats
#define WS_HBF    (1024 + 786432)   // h bf16: 6291456 floats

typedef __attribute__((ext_vector_type(8))) short short8;
typedef __attribute__((ext_vector_type(4))) float f32x4;

__device__ __forceinline__ short8 cvt8(const float4 u, const float4 v) {
    union { short8 s; unsigned w[4]; } r;
    __hip_bfloat162 t;
    t = __float22bfloat162_rn(make_float2(u.x, u.y)); r.w[0] = *(unsigned*)&t;
    t = __float22bfloat162_rn(make_float2(u.z, u.w)); r.w[1] = *(unsigned*)&t;
    t = __float22bfloat162_rn(make_float2(v.x, v.y)); r.w[2] = *(unsigned*)&t;
    t = __float22bfloat162_rn(make_float2(v.z, v.w)); r.w[3] = *(unsigned*)&t;
    return r.s;
}

// async 16B global -> LDS (dest = uniform base + lane*16)
__device__ __forceinline__ void async16(void* lds, const void* g) {
    __builtin_amdgcn_global_load_lds(
        (const __attribute__((address_space(1))) void*)g,
        (__attribute__((address_space(3))) void*)lds, 16, 0, 0);
}

// ---------------------------------------------------------------------------
// Gate logits + fused x->bf16 conversion. grid=64 blocks.
// ---------------------------------------------------------------------------
__global__ __launch_bounds__(256) void gate_logits_kernel(
    const float* __restrict__ x, const float* __restrict__ gate_w,
    float* __restrict__ logits, ushort* __restrict__ xb)
{
    __shared__ float avg[H];
    const int b = blockIdx.x, tid = threadIdx.x;
    for (int c = tid; c < H; c += 256) {
        const float* xp = x  + (size_t)b * T * H + c;
        ushort*      xo = xb + (size_t)b * T * H + c;
        float s = 0.f;
        #pragma unroll
        for (int t = 0; t < T; ++t) {
            const float v = xp[t * H];
            s += v;
            __hip_bfloat16 hb = __float2bfloat16(v);
            xo[t * H] = *(ushort*)&hb;
        }
        avg[c] = s * (1.0f / T);
    }
    __syncthreads();
    const int e = tid >> 5, l = tid & 31;
    float p = 0.f;
    for (int c = l; c < H; c += 32) p += avg[c] * gate_w[e * H + c];
    #pragma unroll
    for (int off = 16; off; off >>= 1) p += __shfl_down(p, off, 32);
    if (l == 0) logits[b * E + e] = p;
}

// ---------------------------------------------------------------------------
// Softmax, top-2, outputs, importance loss, expert tile tables. 1 blk/64 thr.
// ---------------------------------------------------------------------------
__global__ __launch_bounds__(64) void gating_kernel(
    const float* __restrict__ logits, float* __restrict__ beam_w,
    int* __restrict__ sortb, int* __restrict__ t4e, int* __restrict__ t4b,
    int* __restrict__ t4c, float* __restrict__ dout)
{
    __shared__ float sc[Bsz][E];
    __shared__ int sexp[NBEAM];
    const int r = threadIdx.x;
    float v[E];
    float mx = -1e30f;
    #pragma unroll
    for (int e = 0; e < E; ++e) { v[e] = logits[r * E + e]; mx = fmaxf(mx, v[e]); }
    float s = 0.f;
    #pragma unroll
    for (int e = 0; e < E; ++e) { v[e] = expf(v[e] - mx); s += v[e]; }
    const float inv = 1.0f / s;
    #pragma unroll
    for (int e = 0; e < E; ++e) { v[e] *= inv; sc[r][e] = v[e]; }
    float v0 = -1.f, v1 = -1.f; int i0 = 0, i1 = 0;
    #pragma unroll
    for (int e = 0; e < E; ++e) {
        if (v[e] > v0)      { v1 = v0; i1 = i0; v0 = v[e]; i0 = e; }
        else if (v[e] > v1) { v1 = v[e]; i1 = e; }
    }
    const int b0 = 2 * r, b1 = 2 * r + 1;
    dout[OUT_BS + b0] = v0;          dout[OUT_BS + b1] = v1;
    dout[OUT_ER + b0] = (float)i0;   dout[OUT_ER + b1] = (float)i1;
    dout[OUT_BI + b0] = (float)b0;   dout[OUT_BI + b1] = (float)b1;
    beam_w[b0] = v0;  beam_w[b1] = v1;
    sexp[b0] = i0;    sexp[b1] = i1;
    __syncthreads();
    if (r == 0) {
        float imp[E]; float tot = 0.f;
        #pragma unroll
        for (int e = 0; e < E; ++e) {
            float a = 0.f;
            for (int rr = 0; rr < Bsz; ++rr) a += sc[rr][e];
            imp[e] = a; tot += a;
        }
        const float mean = tot / E;
        float var = 0.f;
        #pragma unroll
        for (int e = 0; e < E; ++e) { float d = imp[e] - mean; var += d * d; }
        var /= (E - 1);
        dout[OUT_IL] = var / (mean * mean);
        int cntE[E]; int offE[E]; int posE[E];
        #pragma unroll
        for (int e = 0; e < E; ++e) cntE[e] = 0;
        for (int b = 0; b < NBEAM; ++b) cntE[sexp[b]]++;
        int a0 = 0;
        #pragma unroll
        for (int e = 0; e < E; ++e) { offE[e] = a0; posE[e] = a0; a0 += cntE[e]; }
        for (int b = 0; b < NBEAM; ++b) sortb[posE[sexp[b]]++] = b;
        int t = 0;
        for (int e = 0; e < E; ++e) {
            for (int i = 0; i < cntE[e]; i += 4) {
                t4e[t] = e;
                t4b[t] = offE[e] + i;
                t4c[t] = (cntE[e] - i < 4) ? (cntE[e] - i) : 4;
                ++t;
            }
        }
        for (; t < NT4MAX; ++t) t4c[t] = 0;
    }
}

// ---------------------------------------------------------------------------
// LDS-staged MFMA GEMM (m97-style), expert-grouped M=128 (4 beams).
// Tile: 128(m) x NTILE(n), Ktile=64. 4 waves in 2x2 (64m x NTILE/2 n each).
// A: bf16, async global_load_lds with source-side XOR swizzle.
// W: fp32 -> reg prefetch -> cvt bf16 -> swizzled ds_write.
// LDS layout (both tiles): slot(row, pos) at row*128B + pos*16B,
//   pos = chunk ^ (row & 7); frag reads are ds_read_b128, <=2-way banks.
// MFMA frag layouts (R2/R3-verified): A/B row=lane&15, k=quad*8+j;
//   C/D col=lane&15, row=quad*4+reg.
// ---------------------------------------------------------------------------
template <int KTOT, int NTILE, bool DO_GELU>
__global__ __launch_bounds__(256) void moe_ffn_mfma(
    const ushort* __restrict__ Abf, int a_div,
    const float* __restrict__ Wf32, int w_rows,
    const float* __restrict__ biasb,
    const int* __restrict__ sortb, const int* __restrict__ t4e,
    const int* __restrict__ t4b, const int* __restrict__ t4c,
    const float* __restrict__ beam_w,
    void* __restrict__ Obase)
{
    constexpr int KT = KTOT / 64;       // k-tiles
    constexpr int WF = NTILE / 32;      // n-frags per wave (4 or 2)
    __shared__ __align__(16) ushort sA[128 * 64];
    __shared__ __align__(16) ushort sB[NTILE * 64];

    const int tile = blockIdx.y;
    const int cnt  = t4c[tile];
    if (cnt == 0) return;
    const int e    = t4e[tile];
    const int base = t4b[tile];
    const int tid  = threadIdx.x;
    const int wv   = tid >> 6;
    const int lane = tid & 63;
    const int quad = lane >> 4;
    const int l16  = lane & 15;
    const int mh   = (wv & 1) * 64;
    const int nh   = (wv >> 1) * (NTILE / 2);
    const int n0   = blockIdx.x * NTILE;

    int bm[4];
    #pragma unroll
    for (int s = 0; s < 4; ++s) bm[s] = sortb[base + (s < cnt ? s : cnt - 1)];

    // A DMA source pointers: block instrs j in [0,16), wave does j=wv*4+jj.
    // slot s = j*64+lane: row r = s>>3, pos = s&7, global chunk c = pos^(r&7)
    const ushort* aseg[4];
    #pragma unroll
    for (int jj = 0; jj < 4; ++jj) {
        const int j = wv * 4 + jj;
        const int s = j * 64 + lane;
        const int r = s >> 3;
        const int c = (s & 7) ^ (r & 7);
        aseg[jj] = Abf + (size_t)(bm[r >> 5] / a_div) * T * KTOT
                 + (size_t)(r & 31) * KTOT + c * 8;
    }
    // W: per-thread WF slots; slot s = jj*256+tid: r=s>>3, pos=s&7, c=pos^(r&7)
    const float* wseg[WF];
    int wslot[WF];
    #pragma unroll
    for (int jj = 0; jj < WF; ++jj) {
        const int s = jj * 256 + tid;
        const int r = s >> 3;
        const int c = (s & 7) ^ (r & 7);
        wseg[jj] = Wf32 + (size_t)e * w_rows * KTOT + (size_t)(n0 + r) * KTOT + c * 8;
        wslot[jj] = s * 8;   // ushort index (16B per slot)
    }

    // frag-read row bases
    int arow[4], ar7[4], brow[WF], br7[WF];
    #pragma unroll
    for (int mt = 0; mt < 4; ++mt) {
        const int r = mh + mt * 16 + l16;
        arow[mt] = r * 64; ar7[mt] = r & 7;       // ushort units (128B row)
    }
    #pragma unroll
    for (int nt = 0; nt < WF; ++nt) {
        const int r = nh + nt * 16 + l16;
        brow[nt] = r * 64; br7[nt] = r & 7;
    }

    // prologue: W regs for tile 0, A DMA tile 0
    float4 wr[WF][2];
    #pragma unroll
    for (int jj = 0; jj < WF; ++jj) {
        wr[jj][0] = *(const float4*)(wseg[jj]);
        wr[jj][1] = *(const float4*)(wseg[jj] + 4);
    }
    #pragma unroll
    for (int jj = 0; jj < 4; ++jj)
        async16((char*)sA + (wv * 4 + jj) * 1024, aseg[jj]);

    f32x4 acc[4][WF];
    #pragma unroll
    for (int mt = 0; mt < 4; ++mt)
        #pragma unroll
        for (int nt = 0; nt < WF; ++nt) acc[mt][nt] = {0.f, 0.f, 0.f, 0.f};

    for (int kt = 0; kt < KT; ++kt) {
        // stage W tile kt into LDS (bf16, swizzled)
        #pragma unroll
        for (int jj = 0; jj < WF; ++jj)
            *(short8*)(sB + wslot[jj]) = cvt8(wr[jj][0], wr[jj][1]);
        __syncthreads();   // A-DMA(kt) drained + W writes visible
        if (kt + 1 < KT) {  // prefetch W for kt+1 (overlaps compute below)
            const int kn = (kt + 1) * 64;
            #pragma unroll
            for (int jj = 0; jj < WF; ++jj) {
                wr[jj][0] = *(const float4*)(wseg[jj] + kn);
                wr[jj][1] = *(const float4*)(wseg[jj] + kn + 4);
            }
        }
        #pragma unroll
        for (int ks = 0; ks < 2; ++ks) {
            short8 af[4], wf[WF];
            #pragma unroll
            for (int mt = 0; mt < 4; ++mt)
                af[mt] = *(const short8*)(sA + arow[mt] + (((ks * 4 + quad) ^ ar7[mt]) * 8));
            #pragma unroll
            for (int nt = 0; nt < WF; ++nt)
                wf[nt] = *(const short8*)(sB + brow[nt] + (((ks * 4 + quad) ^ br7[nt]) * 8));
            #pragma unroll
            for (int mt = 0; mt < 4; ++mt)
                #pragma unroll
                for (int nt = 0; nt < WF; ++nt)
                    acc[mt][nt] = __builtin_amdgcn_mfma_f32_16x16x32_bf16(
                        af[mt], wf[nt], acc[mt][nt], 0, 0, 0);
        }
        if (kt + 1 < KT) {
            __syncthreads();   // all waves done reading LDS
            const int kn = (kt + 1) * 64;
            #pragma unroll
            for (int jj = 0; jj < 4; ++jj)
                async16((char*)sA + (wv * 4 + jj) * 1024, aseg[jj] + kn);
        }
    }

    // epilogue
    #pragma unroll
    for (int nt = 0; nt < WF; ++nt) {
        const int n = n0 + nh + nt * 16 + l16;
        const float bias = biasb[(size_t)e * w_rows + n];
        #pragma unroll
        for (int mt = 0; mt < 4; ++mt) {
            const int rowb = mh + mt * 16 + quad * 4;
            const int s = rowb >> 5;
            if (s >= cnt) continue;
            const int b = bm[s];
            const float scale = DO_GELU ? 1.0f : beam_w[b];
            #pragma unroll
            for (int r = 0; r < 4; ++r) {
                const int t = (rowb + r) & 31;
                float vv = acc[mt][nt][r] + bias;
                const size_t idx = (size_t)b * T * w_rows + (size_t)t * w_rows + n;
                if (DO_GELU) {
                    vv = 0.5f * vv * (1.0f + erff(vv * 0.70710678118654752f));
                    ((__hip_bfloat16*)Obase)[idx] = __float2bfloat16(vv);
                } else {
                    ((float*)Obase)[idx] = vv * scale;
                }
            }
        }
    }
}

extern "C" void kernel_launch(void* const* d_in, const int* in_sizes, int n_in,
                              void* d_out, int out_size, void* d_ws, size_t ws_size,
                              hipStream_t stream)
{
    const float* x      = (const float*)d_in[0];
    const float* gate_w = (const float*)d_in[1];
    const float* w1     = (const float*)d_in[2];
    const float* b1     = (const float*)d_in[3];
    const float* w2     = (const float*)d_in[4];
    const float* b2     = (const float*)d_in[5];
    float* out = (float*)d_out;
    float* ws  = (float*)d_ws;

    float*  logits = ws + WS_LOGITS;
    float*  beam_w = ws + WS_BEAMW;
    int*    sortb  = (int*)(ws + WS_SORT);
    int*    t4e    = (int*)(ws + WS_T4E);
    int*    t4b    = (int*)(ws + WS_T4B);
    int*    t4c    = (int*)(ws + WS_T4C);
    ushort* x_bf   = (ushort*)(ws + WS_XBF);
    ushort* h_bf   = (ushort*)(ws + WS_HBF);

    gate_logits_kernel<<<Bsz, 256, 0, stream>>>(x, gate_w, logits, x_bf);
    gating_kernel<<<1, 64, 0, stream>>>(logits, beam_w, sortb, t4e, t4b, t4c, out);
    // GEMM1 + GELU: M=128/tile, N=DFF in 128-strips, K=768
    moe_ffn_mfma<H, 128, true><<<dim3(DFF / 128, NT4MAX), 256, 0, stream>>>(
        x_bf, NB, w1, DFF, b1, sortb, t4e, t4b, t4c, beam_w, (void*)h_bf);
    // GEMM2 + scale: M=128/tile, N=H in 64-strips, K=3072
    moe_ffn_mfma<DFF, 64, false><<<dim3(H / 64, NT4MAX), 256, 0, stream>>>(
        h_bf, 1, w2, H, b2, sortb, t4e, t4b, t4c, beam_w, out);
}

// Round 5
// 306.714 us; speedup vs baseline: 2.4366x; 1.0322x over previous
//
#include <hip/hip_runtime.h>
#include <hip/hip_bf16.h>
#include <math.h>

#define Bsz 64
#define T 32
#define H 768
#define E 8
#define NB 2
#define DFF 3072
#define NBEAM (Bsz * NB)   // 128
#define NT4MAX 40

// d_out layout (floats):
#define OUT_BS 3145728
#define OUT_ER 3145856
#define OUT_BI 3145984
#define OUT_IL 3146112

// ws layout (float units):
#define WS_LOGITS 0                 // 3*512 chunked partial logits
#define WS_BEAMW  1536              // 128
#define WS_SORT   1664              // 128 int
#define WS_T4E    1792              // 40 int
#define WS_T4B    1832              // 40 int
#define WS_T4C    1872              // 40 int
#define WS_XBF    2048              // x bf16: 786432 floats
#define WS_HBF    (2048 + 786432)   // h bf16: 6291456 floats

typedef __attribute__((ext_vector_type(8))) short short8;
typedef __attribute__((ext_vector_type(4))) float f32x4;

__device__ __forceinline__ short8 cvt8(const float4 u, const float4 v) {
    union { short8 s; unsigned w[4]; } r;
    __hip_bfloat162 t;
    t = __float22bfloat162_rn(make_float2(u.x, u.y)); r.w[0] = *(unsigned*)&t;
    t = __float22bfloat162_rn(make_float2(u.z, u.w)); r.w[1] = *(unsigned*)&t;
    t = __float22bfloat162_rn(make_float2(v.x, v.y)); r.w[2] = *(unsigned*)&t;
    t = __float22bfloat162_rn(make_float2(v.z, v.w)); r.w[3] = *(unsigned*)&t;
    return r.s;
}

// async 16B global -> LDS (dest = uniform base + lane*16)
__device__ __forceinline__ void async16(void* lds, const void* g) {
    __builtin_amdgcn_global_load_lds(
        (const __attribute__((address_space(1))) void*)g,
        (__attribute__((address_space(3))) void*)lds, 16, 0, 0);
}

// ---------------------------------------------------------------------------
// x fp32 -> bf16, fully coalesced. 1536 blocks.
// ---------------------------------------------------------------------------
__global__ __launch_bounds__(256) void conv_x_kernel(
    const float* __restrict__ x, ushort* __restrict__ xb, int n4)
{
    const int i = blockIdx.x * 256 + threadIdx.x;
    if (i >= n4) return;
    const float4 v = ((const float4*)x)[i];
    __hip_bfloat162 t0 = __float22bfloat162_rn(make_float2(v.x, v.y));
    __hip_bfloat162 t1 = __float22bfloat162_rn(make_float2(v.z, v.w));
    ushort4 o;
    o.x = (*(unsigned*)&t0) & 0xffff; o.y = (*(unsigned*)&t0) >> 16;
    o.z = (*(unsigned*)&t1) & 0xffff; o.w = (*(unsigned*)&t1) >> 16;
    ((ushort4*)xb)[i] = o;
}

// ---------------------------------------------------------------------------
// Gate partial logits: grid (3 chunks, 64 batches). Block handles 256 cols:
// column mean over T, dot with gate_w chunk for all 8 experts. Deterministic
// (no atomics): writes logits_part[chunk][b][e].
// ---------------------------------------------------------------------------
__global__ __launch_bounds__(256) void gate_partial_kernel(
    const float* __restrict__ x, const float* __restrict__ gate_w,
    float* __restrict__ logits_part)
{
    __shared__ float part[4][E];
    const int chunk = blockIdx.x, b = blockIdx.y;
    const int tid = threadIdx.x, wv = tid >> 6, lane = tid & 63;
    const int c = chunk * 256 + tid;
    const float* xp = x + (size_t)b * T * H + c;
    float s = 0.f;
    #pragma unroll
    for (int t = 0; t < T; ++t) s += xp[t * H];
    const float avg = s * (1.0f / T);
    #pragma unroll
    for (int e = 0; e < E; ++e) {
        float p = avg * gate_w[e * H + c];
        #pragma unroll
        for (int off = 32; off; off >>= 1) p += __shfl_down(p, off, 64);
        if (lane == 0) part[wv][e] = p;
    }
    __syncthreads();
    if (tid < E) {
        float t = part[0][tid] + part[1][tid] + part[2][tid] + part[3][tid];
        logits_part[chunk * 512 + b * E + tid] = t;
    }
}

// ---------------------------------------------------------------------------
// Gating: softmax, top-2, outputs, importance loss, expert tables.
// 1 block, 64 threads, FULLY parallel (ballot/popcount sort, shfl reduce).
// ---------------------------------------------------------------------------
__global__ __launch_bounds__(64) void gating_kernel(
    const float* __restrict__ logits_part, float* __restrict__ beam_w,
    int* __restrict__ sortb, int* __restrict__ t4e, int* __restrict__ t4b,
    int* __restrict__ t4c, float* __restrict__ dout)
{
    const int r = threadIdx.x;  // batch row 0..63
    float v[E];
    float mx = -1e30f;
    #pragma unroll
    for (int e = 0; e < E; ++e) {
        v[e] = logits_part[r * E + e] + logits_part[512 + r * E + e]
             + logits_part[1024 + r * E + e];
        mx = fmaxf(mx, v[e]);
    }
    float s = 0.f;
    #pragma unroll
    for (int e = 0; e < E; ++e) { v[e] = expf(v[e] - mx); s += v[e]; }
    const float inv = 1.0f / s;
    #pragma unroll
    for (int e = 0; e < E; ++e) v[e] *= inv;
    // top-2 (stable: lower index wins ties, matches jax.lax.top_k)
    float v0 = -1.f, v1 = -1.f; int i0 = 0, i1 = 0;
    #pragma unroll
    for (int e = 0; e < E; ++e) {
        if (v[e] > v0)      { v1 = v0; i1 = i0; v0 = v[e]; i0 = e; }
        else if (v[e] > v1) { v1 = v[e]; i1 = e; }
    }
    const int b0 = 2 * r, b1 = 2 * r + 1;
    dout[OUT_BS + b0] = v0;          dout[OUT_BS + b1] = v1;
    dout[OUT_ER + b0] = (float)i0;   dout[OUT_ER + b1] = (float)i1;
    dout[OUT_BI + b0] = (float)b0;   dout[OUT_BI + b1] = (float)b1;
    beam_w[b0] = v0;  beam_w[b1] = v1;
    // importance loss via 64-lane butterfly reductions
    float imp[E];
    #pragma unroll
    for (int e = 0; e < E; ++e) {
        float t = v[e];
        #pragma unroll
        for (int off = 1; off < 64; off <<= 1) t += __shfl_xor(t, off, 64);
        imp[e] = t;
    }
    if (r == 0) {
        float tot = 0.f;
        #pragma unroll
        for (int e = 0; e < E; ++e) tot += imp[e];
        const float mean = tot / E;
        float var = 0.f;
        #pragma unroll
        for (int e = 0; e < E; ++e) { float d = imp[e] - mean; var += d * d; }
        var /= (E - 1);
        dout[OUT_IL] = var / (mean * mean);
    }
    // expert-grouped sort via ballots (beams 2r even-mask, 2r+1 odd-mask)
    unsigned long long m0[E], m1[E];
    #pragma unroll
    for (int e = 0; e < E; ++e) {
        m0[e] = __ballot(i0 == e);
        m1[e] = __ballot(i1 == e);
    }
    int cnt[E], off[E];
    int a0 = 0;
    #pragma unroll
    for (int e = 0; e < E; ++e) {
        cnt[e] = __popcll(m0[e]) + __popcll(m1[e]);
        off[e] = a0; a0 += cnt[e];
    }
    const unsigned long long below = (r == 0) ? 0ull : ((1ull << r) - 1ull);
    const unsigned long long incl  = below | (1ull << r);
    const int pos0 = __popcll(m0[i0] & below) + __popcll(m1[i0] & below);
    const int pos1 = __popcll(m0[i1] & incl)  + __popcll(m1[i1] & below);
    sortb[off[i0] + pos0] = b0;
    sortb[off[i1] + pos1] = b1;
    // 4-beam tile table
    int tb[E]; int tc = 0;
    #pragma unroll
    for (int e = 0; e < E; ++e) { tb[e] = tc; tc += (cnt[e] + 3) >> 2; }
    if (r < E) {
        const int e = r;
        int j = tb[e];
        for (int i = 0; i < cnt[e]; i += 4, ++j) {
            t4e[j] = e;
            t4b[j] = off[e] + i;
            t4c[j] = (cnt[e] - i < 4) ? (cnt[e] - i) : 4;
        }
    }
    for (int t = tc + r; t < NT4MAX; t += 64) t4c[t] = 0;
}

// ---------------------------------------------------------------------------
// LDS double-buffered MFMA GEMM, single barrier per k-tile.
// Tile: 128(m: 4 beams of one expert) x NTILE(n), Ktile=64.
// 4 waves in 2x2; wave tile 64m x NTILE/2 n.
// A: bf16 via async global_load_lds (src-side XOR swizzle).
// W: fp32 -> reg prefetch -> cvt bf16 -> swizzled ds_write.
// Pipeline per ktile: cvt+write W(kt) | barrier | issue A-DMA(kt+1)+load
// W(kt+1) into OTHER buffer | compute(kt).  Barrier's vmcnt(0) catches the
// DMA issued one compute-phase earlier -> latency hidden.
// ---------------------------------------------------------------------------
template <int KTOT, int NTILE, bool DO_GELU>
__global__ __launch_bounds__(256, 2) void moe_ffn_mfma(
    const ushort* __restrict__ Abf, int a_div,
    const float* __restrict__ Wf32, int w_rows,
    const float* __restrict__ biasb,
    const int* __restrict__ sortb, const int* __restrict__ t4e,
    const int* __restrict__ t4b, const int* __restrict__ t4c,
    const float* __restrict__ beam_w,
    void* __restrict__ Obase)
{
    constexpr int KT = KTOT / 64;
    constexpr int WF = NTILE / 32;      // n-frags per wave / W slots per thread
    __shared__ __align__(16) ushort sA[2][128 * 64];
    __shared__ __align__(16) ushort sB[2][NTILE * 64];

    const int tile = blockIdx.y;
    const int cnt  = t4c[tile];
    if (cnt == 0) return;
    const int e    = t4e[tile];
    const int base = t4b[tile];
    const int tid  = threadIdx.x;
    const int wv   = tid >> 6;
    const int lane = tid & 63;
    const int quad = lane >> 4;
    const int l16  = lane & 15;
    const int mh   = (wv & 1) * 64;
    const int nh   = (wv >> 1) * (NTILE / 2);
    const int n0   = blockIdx.x * NTILE;

    int bm[4];
    #pragma unroll
    for (int s = 0; s < 4; ++s) bm[s] = sortb[base + (s < cnt ? s : cnt - 1)];

    // A DMA sources: wave does slots j=wv*4+jj; slot s=j*64+lane:
    // row=s>>3, pos=s&7, source chunk c = pos^(row&7)
    const ushort* aseg[4];
    #pragma unroll
    for (int jj = 0; jj < 4; ++jj) {
        const int s = (wv * 4 + jj) * 64 + lane;
        const int r = s >> 3;
        const int c = (s & 7) ^ (r & 7);
        aseg[jj] = Abf + (size_t)(bm[r >> 5] / a_div) * T * KTOT
                 + (size_t)(r & 31) * KTOT + c * 8;
    }
    // W slots: s=jj*256+tid: row=s>>3, c=(s&7)^(row&7)
    const float* wseg[WF];
    int wslot[WF];
    #pragma unroll
    for (int jj = 0; jj < WF; ++jj) {
        const int s = jj * 256 + tid;
        const int r = s >> 3;
        const int c = (s & 7) ^ (r & 7);
        wseg[jj] = Wf32 + (size_t)e * w_rows * KTOT + (size_t)(n0 + r) * KTOT + c * 8;
        wslot[jj] = s * 8;
    }

    int arow[4], ar7[4], brow[WF], br7[WF];
    #pragma unroll
    for (int mt = 0; mt < 4; ++mt) {
        const int r = mh + mt * 16 + l16;
        arow[mt] = r * 64; ar7[mt] = r & 7;
    }
    #pragma unroll
    for (int nt = 0; nt < WF; ++nt) {
        const int r = nh + nt * 16 + l16;
        brow[nt] = r * 64; br7[nt] = r & 7;
    }

    // prologue: tile 0 in flight
    float4 wr[WF][2];
    #pragma unroll
    for (int jj = 0; jj < WF; ++jj) {
        wr[jj][0] = *(const float4*)(wseg[jj]);
        wr[jj][1] = *(const float4*)(wseg[jj] + 4);
    }
    #pragma unroll
    for (int jj = 0; jj < 4; ++jj)
        async16((char*)sA[0] + (wv * 4 + jj) * 1024, aseg[jj]);

    f32x4 acc[4][WF];
    #pragma unroll
    for (int mt = 0; mt < 4; ++mt)
        #pragma unroll
        for (int nt = 0; nt < WF; ++nt) acc[mt][nt] = {0.f, 0.f, 0.f, 0.f};

    for (int kt = 0; kt < KT; ++kt) {
        const int p = kt & 1;
        // stage W(kt) into LDS (waits its global loads via dependency)
        #pragma unroll
        for (int jj = 0; jj < WF; ++jj)
            *(short8*)(sB[p] + wslot[jj]) = cvt8(wr[jj][0], wr[jj][1]);
        __syncthreads();   // drains A-DMA(kt) + publishes W(kt)
        if (kt + 1 < KT) { // prefetch NEXT tile into other buffer (hidden by compute)
            const int kn = (kt + 1) * 64;
            #pragma unroll
            for (int jj = 0; jj < 4; ++jj)
                async16((char*)sA[1 - p] + (wv * 4 + jj) * 1024, aseg[jj] + kn);
            #pragma unroll
            for (int jj = 0; jj < WF; ++jj) {
                wr[jj][0] = *(const float4*)(wseg[jj] + kn);
                wr[jj][1] = *(const float4*)(wseg[jj] + kn + 4);
            }
        }
        // compute(kt)
        #pragma unroll
        for (int ks = 0; ks < 2; ++ks) {
            short8 af[4], wf[WF];
            #pragma unroll
            for (int mt = 0; mt < 4; ++mt)
                af[mt] = *(const short8*)(sA[p] + arow[mt] + (((ks * 4 + quad) ^ ar7[mt]) * 8));
            #pragma unroll
            for (int nt = 0; nt < WF; ++nt)
                wf[nt] = *(const short8*)(sB[p] + brow[nt] + (((ks * 4 + quad) ^ br7[nt]) * 8));
            #pragma unroll
            for (int mt = 0; mt < 4; ++mt)
                #pragma unroll
                for (int nt = 0; nt < WF; ++nt)
                    acc[mt][nt] = __builtin_amdgcn_mfma_f32_16x16x32_bf16(
                        af[mt], wf[nt], acc[mt][nt], 0, 0, 0);
        }
    }

    // epilogue
    #pragma unroll
    for (int nt = 0; nt < WF; ++nt) {
        const int n = n0 + nh + nt * 16 + l16;
        const float bias = biasb[(size_t)e * w_rows + n];
        #pragma unroll
        for (int mt = 0; mt < 4; ++mt) {
            const int rowb = mh + mt * 16 + quad * 4;
            const int s = rowb >> 5;
            if (s >= cnt) continue;
            const int b = bm[s];
            const float scale = DO_GELU ? 1.0f : beam_w[b];
            #pragma unroll
            for (int r = 0; r < 4; ++r) {
                const int t = (rowb + r) & 31;
                float vv = acc[mt][nt][r] + bias;
                const size_t idx = (size_t)b * T * w_rows + (size_t)t * w_rows + n;
                if (DO_GELU) {
                    vv = 0.5f * vv * (1.0f + erff(vv * 0.70710678118654752f));
                    ((__hip_bfloat16*)Obase)[idx] = __float2bfloat16(vv);
                } else {
                    ((float*)Obase)[idx] = vv * scale;
                }
            }
        }
    }
}

extern "C" void kernel_launch(void* const* d_in, const int* in_sizes, int n_in,
                              void* d_out, int out_size, void* d_ws, size_t ws_size,
                              hipStream_t stream)
{
    const float* x      = (const float*)d_in[0];
    const float* gate_w = (const float*)d_in[1];
    const float* w1     = (const float*)d_in[2];
    const float* b1     = (const float*)d_in[3];
    const float* w2     = (const float*)d_in[4];
    const float* b2     = (const float*)d_in[5];
    float* out = (float*)d_out;
    float* ws  = (float*)d_ws;

    float*  logits = ws + WS_LOGITS;
    float*  beam_w = ws + WS_BEAMW;
    int*    sortb  = (int*)(ws + WS_SORT);
    int*    t4e    = (int*)(ws + WS_T4E);
    int*    t4b    = (int*)(ws + WS_T4B);
    int*    t4c    = (int*)(ws + WS_T4C);
    ushort* x_bf   = (ushort*)(ws + WS_XBF);
    ushort* h_bf   = (ushort*)(ws + WS_HBF);

    conv_x_kernel<<<(Bsz * T * H / 4 + 255) / 256, 256, 0, stream>>>(
        x, x_bf, Bsz * T * H / 4);
    gate_partial_kernel<<<dim3(3, Bsz), 256, 0, stream>>>(x, gate_w, logits);
    gating_kernel<<<1, 64, 0, stream>>>(logits, beam_w, sortb, t4e, t4b, t4c, out);
    // GEMM1 + GELU: M=128/tile, N=DFF in 128-strips, K=768
    moe_ffn_mfma<H, 128, true><<<dim3(DFF / 128, NT4MAX), 256, 0, stream>>>(
        x_bf, NB, w1, DFF, b1, sortb, t4e, t4b, t4c, beam_w, (void*)h_bf);
    // GEMM2 + scale: M=128/tile, N=H in 64-strips, K=3072
    moe_ffn_mfma<DFF, 64, false><<<dim3(H / 64, NT4MAX), 256, 0, stream>>>(
        h_bf, 1, w2, H, b2, sortb, t4e, t4b, t4c, beam_w, out);
}